// Round 1
// baseline (774.785 us; speedup 1.0000x reference)
//
#include <hip/hip_runtime.h>
#include <hip/hip_bf16.h>

// ---------- constants ----------
#define T_TOK   100352      // 32 * 3136 tokens
#define NWIN    2048        // 32 * 64 windows
#define EPS_LN  1e-5f

typedef __attribute__((ext_vector_type(8))) short bf16x8;
typedef __attribute__((ext_vector_type(4))) float f32x4;

// ---------- helpers ----------
__device__ inline float bf2f(unsigned short u) {
  union { unsigned int i; float f; } c; c.i = ((unsigned int)u) << 16; return c.f;
}
__device__ inline unsigned short f2bf(float f) {
  union { float f; unsigned int i; } c; c.f = f;
  unsigned int x = c.i;
  x += 0x7fffu + ((x >> 16) & 1u);   // round-to-nearest-even
  return (unsigned short)(x >> 16);
}
__device__ inline bf16x8 ld8(const unsigned short* p) {
  return *reinterpret_cast<const bf16x8*>(p);
}

// window-ordered row r (win*49 + n) -> token index (b*3136 + l)
__device__ inline int win_row_to_token(int r) {
  int win = r / 49, n = r % 49;
  int b  = win >> 6, w2 = win & 63;
  int wi = w2 >> 3,  wj = w2 & 7;
  int rr = n / 7,    cc = n % 7;
  return b * 3136 + (wi * 7 + rr) * 56 + (wj * 7 + cc);
}

// ---------- kernel 0: weights -> bf16, transposed to [N][K] ----------
__global__ void prep_weights(const float* __restrict__ qkv_w,
                             const float* __restrict__ proj_w,
                             const float* __restrict__ w1,
                             const float* __restrict__ w2,
                             unsigned short* __restrict__ wts) {
  int i = blockIdx.x * 256 + threadIdx.x;
  unsigned short* qkvt  = wts;            // [384][128]
  unsigned short* projt = wts + 49152;    // [128][128]
  unsigned short* w1t   = wts + 65536;    // [512][128]
  unsigned short* w2t   = wts + 131072;   // [128][512]
  if (i < 49152) {
    int n = i >> 7, k = i & 127; qkvt[i] = f2bf(qkv_w[k * 384 + n]);
  } else if (i < 65536) {
    int e = i - 49152; int n = e >> 7, k = e & 127; projt[e] = f2bf(proj_w[k * 128 + n]);
  } else if (i < 131072) {
    int e = i - 65536; int n = e >> 7, k = e & 127; w1t[e] = f2bf(w1[k * 512 + n]);
  } else if (i < 196608) {
    int e = i - 131072; int n = e >> 9, k = e & 511; w2t[e] = f2bf(w2[k * 128 + n]);
  }
}

// ---------- layernorm (optionally gathering window-partition order) ----------
template<bool WINMAP>
__global__ __launch_bounds__(256) void ln_kernel(const float* __restrict__ x,
                                                 const float* __restrict__ w,
                                                 const float* __restrict__ b,
                                                 unsigned short* __restrict__ out) {
  int r    = blockIdx.x * 4 + (threadIdx.x >> 6);
  int lane = threadIdx.x & 63;
  int src  = WINMAP ? win_row_to_token(r) : r;
  float2 v = *reinterpret_cast<const float2*>(x + (long)src * 128 + lane * 2);
  float s  = v.x + v.y;
  float s2 = v.x * v.x + v.y * v.y;
#pragma unroll
  for (int off = 32; off; off >>= 1) {
    s  += __shfl_xor(s,  off);
    s2 += __shfl_xor(s2, off);
  }
  float mu  = s * (1.f / 128.f);
  float var = s2 * (1.f / 128.f) - mu * mu;
  float inv = rsqrtf(var + EPS_LN);
  int c = lane * 2;
  float2 wv = *reinterpret_cast<const float2*>(w + c);
  float2 bv = *reinterpret_cast<const float2*>(b + c);
  float y0 = (v.x - mu) * inv * wv.x + bv.x;
  float y1 = (v.y - mu) * inv * wv.y + bv.y;
  unsigned int pk = ((unsigned int)f2bf(y1) << 16) | (unsigned int)f2bf(y0);
  *reinterpret_cast<unsigned int*>(out + (long)r * 128 + c) = pk;
}

// ---------- generic 64x64-tile bf16 MFMA GEMM with fused epilogues ----------
// A: [M][K] bf16 row-major.  Wt: [N][K] bf16 (transposed weights).
// EPI 0: qkv   -> bf16 out, stride 384, +bias
// EPI 1: proj  -> f32 out1[t] = res(x)[t] + acc + bias, window-reverse map
// EPI 2: mlp1  -> bf16 out, stride 512, gelu(acc+bias)
// EPI 3: mlp2  -> f32 d_out[r] = res(out1)[r] + acc + bias
template<int EPI, int KSTEPS>
__global__ __launch_bounds__(256) void gemm_k(const unsigned short* __restrict__ A,
                                              const unsigned short* __restrict__ Wt,
                                              const float* __restrict__ bias,
                                              void* __restrict__ out,
                                              const float* __restrict__ res) {
  const int K = KSTEPS * 32;
  int lane = threadIdx.x & 63;
  int wid  = threadIdx.x >> 6;
  int rowBase = blockIdx.x * 64 + wid * 16;
  int colBase = blockIdx.y * 64;
  int m  = lane & 15;
  int kg = lane >> 4;
  f32x4 acc[4] = {};
  const unsigned short* Ap = A  + (long)(rowBase + m) * K + kg * 8;
  const unsigned short* Bp = Wt + (long)(colBase + m) * K + kg * 8;
  for (int ks = 0; ks < KSTEPS; ks++) {
    bf16x8 a = ld8(Ap + ks * 32);
#pragma unroll
    for (int j = 0; j < 4; j++) {
      bf16x8 bb = ld8(Bp + j * 16 * K + ks * 32);
      acc[j] = __builtin_amdgcn_mfma_f32_16x16x32_bf16(a, bb, acc[j], 0, 0, 0);
    }
  }
#pragma unroll
  for (int j = 0; j < 4; j++) {
    int col = colBase + j * 16 + m;
    float bv = bias[col];
#pragma unroll
    for (int rgi = 0; rgi < 4; rgi++) {
      int row = rowBase + kg * 4 + rgi;
      float v = acc[j][rgi] + bv;
      if (EPI == 0) {
        ((unsigned short*)out)[(long)row * 384 + col] = f2bf(v);
      } else if (EPI == 1) {
        int t = win_row_to_token(row);
        ((float*)out)[(long)t * 128 + col] = res[(long)t * 128 + col] + v;
      } else if (EPI == 2) {
        float g = 0.5f * v * (1.0f + erff(v * 0.70710678118654752f));
        ((unsigned short*)out)[(long)row * 512 + col] = f2bf(g);
      } else {
        ((float*)out)[(long)row * 128 + col] = res[(long)row * 128 + col] + v;
      }
    }
  }
}

// ---------- window attention: one block per window, one wave per head ----------
__global__ __launch_bounds__(256) void attn_kernel(const unsigned short* __restrict__ qkv,
                                                   const float* __restrict__ rpb,
                                                   unsigned short* __restrict__ out) {
  __shared__ unsigned int lds[49 * 193];   // padded rows: 192 dwords data + 1 pad
  int win = blockIdx.x;
  const unsigned int* src = (const unsigned int*)(qkv + (long)win * 49 * 384);
  for (int i = threadIdx.x; i < 49 * 192; i += 256)
    lds[(i / 192) * 193 + (i % 192)] = src[i];
  __syncthreads();

  int h    = threadIdx.x >> 6;
  int lane = threadIdx.x & 63;
  int w2 = win & 63, wi = w2 >> 3, wj = w2 & 7;
  int mm = lane;
  int msafe = (mm < 49) ? mm : 0;
  int mr = msafe / 7, mc = msafe % 7;
  // shift-mask region code of key position m (only boundary windows differ)
  int regm = ((wi == 7) ? (mr < 4 ? 3 : 6) : 0) + ((wj == 7) ? (mc < 4 ? 1 : 2) : 0);
  const float scale = 0.17677669529663687f;  // 32^-0.5
  const unsigned int*  krow = lds + msafe * 193 + 64 + h * 16;
  const unsigned short* ldsu = (const unsigned short*)lds;
  int d = lane & 31;

  for (int r = 0; r < 49; r++) {
    const unsigned int* qrow = lds + r * 193 + h * 16;
    float s = 0.f;
#pragma unroll
    for (int dd = 0; dd < 16; dd++) {
      unsigned int qw = qrow[dd], kw = krow[dd];
      s += bf2f((unsigned short)qw) * bf2f((unsigned short)kw)
         + bf2f((unsigned short)(qw >> 16)) * bf2f((unsigned short)(kw >> 16));
    }
    s *= scale;
    int rr_ = r / 7, rc_ = r % 7;
    int idx = (rr_ - mr + 6) * 13 + (rc_ - mc + 6);
    s += rpb[idx * 4 + h];
    int regr = ((wi == 7) ? (rr_ < 4 ? 3 : 6) : 0) + ((wj == 7) ? (rc_ < 4 ? 1 : 2) : 0);
    if (regr != regm) s -= 100.f;
    if (mm >= 49) s = -1e30f;
    float mx = s;
#pragma unroll
    for (int off = 32; off; off >>= 1) mx = fmaxf(mx, __shfl_xor(mx, off));
    float p = (mm < 49) ? __expf(s - mx) : 0.f;
    float sum = p;
#pragma unroll
    for (int off = 32; off; off >>= 1) sum += __shfl_xor(sum, off);
    p /= sum;
    // PV: broadcast p from lane m via shuffle, each lane owns one d
    float acc = 0.f;
    for (int m2 = 0; m2 < 49; m2++) {
      float pm = __shfl(p, m2);
      acc += pm * bf2f(ldsu[(m2 * 193 + 128 + h * 16) * 2 + d]);
    }
    if (lane < 32)
      out[((long)win * 49 + r) * 128 + h * 32 + d] = f2bf(acc);
  }
}

// ---------- launch ----------
extern "C" void kernel_launch(void* const* d_in, const int* in_sizes, int n_in,
                              void* d_out, int out_size, void* d_ws, size_t ws_size,
                              hipStream_t stream) {
  (void)in_sizes; (void)n_in; (void)out_size; (void)ws_size;
  const float* x      = (const float*)d_in[0];
  const float* qkv_w  = (const float*)d_in[1];
  const float* qkv_b  = (const float*)d_in[2];
  const float* proj_w = (const float*)d_in[3];
  const float* proj_b = (const float*)d_in[4];
  const float* rpb    = (const float*)d_in[5];
  const float* ln1_w  = (const float*)d_in[6];
  const float* ln1_b  = (const float*)d_in[7];
  const float* ln2_w  = (const float*)d_in[8];
  const float* ln2_b  = (const float*)d_in[9];
  const float* w1     = (const float*)d_in[10];
  const float* b1     = (const float*)d_in[11];
  const float* w2     = (const float*)d_in[12];
  const float* b2     = (const float*)d_in[13];

  char* ws = (char*)d_ws;
  // layout (bytes):
  //   0        : weights bf16 (393216)
  //   393216   : hb [T][128] bf16 (25690112)  -- later aliased by attnout, then by g
  //   26083328 : qkv [T][384] bf16 (77070336) -- later part of g
  //   103153664: out1 [T][128] f32 (51380224)
  //   154533888: m [T][128] bf16 (25690112)   -- total 180224000
  unsigned short* wts   = (unsigned short*)ws;
  unsigned short* hb    = (unsigned short*)(ws + 393216);
  unsigned short* qkv   = (unsigned short*)(ws + 26083328);
  unsigned short* attno = hb;                      // alias: hb dead after QKV gemm
  unsigned short* g     = hb;                      // alias: spans hb+qkv regions
  float*          out1  = (float*)(ws + 103153664);
  unsigned short* mbuf  = (unsigned short*)(ws + 154533888);

  prep_weights<<<768, 256, 0, stream>>>(qkv_w, proj_w, w1, w2, wts);
  ln_kernel<true><<<T_TOK / 4, 256, 0, stream>>>(x, ln1_w, ln1_b, hb);
  gemm_k<0, 4><<<dim3(T_TOK / 64, 6), 256, 0, stream>>>(hb, wts, qkv_b, qkv, nullptr);
  attn_kernel<<<NWIN, 256, 0, stream>>>(qkv, rpb, attno);
  gemm_k<1, 4><<<dim3(T_TOK / 64, 2), 256, 0, stream>>>(attno, wts + 49152, proj_b, out1, x);
  ln_kernel<false><<<T_TOK / 4, 256, 0, stream>>>(out1, ln2_w, ln2_b, mbuf);
  gemm_k<2, 4><<<dim3(T_TOK / 64, 8), 256, 0, stream>>>(mbuf, wts + 65536, b1, g, nullptr);
  gemm_k<3, 16><<<dim3(T_TOK / 64, 2), 256, 0, stream>>>(g, wts + 131072, b2, (float*)d_out, out1);
}

// Round 2
// 451.273 us; speedup vs baseline: 1.7169x; 1.7169x over previous
//
#include <hip/hip_runtime.h>
#include <hip/hip_bf16.h>

// ---------- constants ----------
#define T_TOK   100352      // 32 * 3136 tokens
#define NWIN    2048        // 32 * 64 windows
#define EPS_LN  1e-5f

typedef __attribute__((ext_vector_type(8))) short bf16x8;
typedef __attribute__((ext_vector_type(4))) float f32x4;

// ---------- helpers ----------
__device__ inline float bf2f(unsigned short u) {
  union { unsigned int i; float f; } c; c.i = ((unsigned int)u) << 16; return c.f;
}
__device__ inline unsigned short f2bf(float f) {
  union { float f; unsigned int i; } c; c.f = f;
  unsigned int x = c.i;
  x += 0x7fffu + ((x >> 16) & 1u);   // round-to-nearest-even
  return (unsigned short)(x >> 16);
}
__device__ inline bf16x8 ld8(const unsigned short* p) {
  return *reinterpret_cast<const bf16x8*>(p);
}

// window-ordered row r (win*49 + n) -> token index (b*3136 + l)
__device__ inline int win_row_to_token(int r) {
  int win = r / 49, n = r % 49;
  int b  = win >> 6, w2 = win & 63;
  int wi = w2 >> 3,  wj = w2 & 7;
  int rr = n / 7,    cc = n % 7;
  return b * 3136 + (wi * 7 + rr) * 56 + (wj * 7 + cc);
}

// ---------- kernel 0: weights -> bf16, transposed to [N][K] ----------
__global__ void prep_weights(const float* __restrict__ qkv_w,
                             const float* __restrict__ proj_w,
                             const float* __restrict__ w1,
                             const float* __restrict__ w2,
                             unsigned short* __restrict__ wts) {
  int i = blockIdx.x * 256 + threadIdx.x;
  unsigned short* qkvt  = wts;            // [384][128]
  unsigned short* projt = wts + 49152;    // [128][128]
  unsigned short* w1t   = wts + 65536;    // [512][128]
  unsigned short* w2t   = wts + 131072;   // [128][512]
  if (i < 49152) {
    int n = i >> 7, k = i & 127; qkvt[i] = f2bf(qkv_w[k * 384 + n]);
  } else if (i < 65536) {
    int e = i - 49152; int n = e >> 7, k = e & 127; projt[e] = f2bf(proj_w[k * 128 + n]);
  } else if (i < 131072) {
    int e = i - 65536; int n = e >> 7, k = e & 127; w1t[e] = f2bf(w1[k * 512 + n]);
  } else if (i < 196608) {
    int e = i - 131072; int n = e >> 9, k = e & 511; w2t[e] = f2bf(w2[k * 128 + n]);
  }
}

// ---------- kernel 0b: bias+mask table in C-fragment order ----------
// cls2[cl][h][rt][ct][lane][reg] : 4*4*4*4*64*4 floats = 256 KB
__global__ void prep_cls(const float* __restrict__ rpb, float* __restrict__ cls2) {
  int i = blockIdx.x * 256 + threadIdx.x;          // 65536 total
  int reg = i & 3, lane = (i >> 2) & 63, ct = (i >> 8) & 3, rt = (i >> 10) & 3,
      h = (i >> 12) & 3, cl = (i >> 14) & 3;
  int n = rt * 16 + ((lane >> 4) << 2) + reg;
  int m = ct * 16 + (lane & 15);
  float v = -30000.f;                               // padding mask (finite, exp->0)
  if (n < 49 && m < 49) {
    int nr = n / 7, nc = n % 7, mr = m / 7, mc = m % 7;
    v = rpb[((nr - mr + 6) * 13 + (nc - mc + 6)) * 4 + h];
    int regn = ((cl & 2) ? (nr < 4 ? 3 : 6) : 0) + ((cl & 1) ? (nc < 4 ? 1 : 2) : 0);
    int regm = ((cl & 2) ? (mr < 4 ? 3 : 6) : 0) + ((cl & 1) ? (mc < 4 ? 1 : 2) : 0);
    if (regn != regm) v -= 100.f;
  }
  cls2[i] = v;
}

// ---------- layernorm (optionally gathering window-partition order) ----------
template<bool WINMAP>
__global__ __launch_bounds__(256) void ln_kernel(const float* __restrict__ x,
                                                 const float* __restrict__ w,
                                                 const float* __restrict__ b,
                                                 unsigned short* __restrict__ out) {
  int r    = blockIdx.x * 4 + (threadIdx.x >> 6);
  int lane = threadIdx.x & 63;
  int src  = WINMAP ? win_row_to_token(r) : r;
  float2 v = *reinterpret_cast<const float2*>(x + (long)src * 128 + lane * 2);
  float s  = v.x + v.y;
  float s2 = v.x * v.x + v.y * v.y;
#pragma unroll
  for (int off = 32; off; off >>= 1) {
    s  += __shfl_xor(s,  off);
    s2 += __shfl_xor(s2, off);
  }
  float mu  = s * (1.f / 128.f);
  float var = s2 * (1.f / 128.f) - mu * mu;
  float inv = rsqrtf(var + EPS_LN);
  int c = lane * 2;
  float2 wv = *reinterpret_cast<const float2*>(w + c);
  float2 bv = *reinterpret_cast<const float2*>(b + c);
  float y0 = (v.x - mu) * inv * wv.x + bv.x;
  float y1 = (v.y - mu) * inv * wv.y + bv.y;
  unsigned int pk = ((unsigned int)f2bf(y1) << 16) | (unsigned int)f2bf(y0);
  *reinterpret_cast<unsigned int*>(out + (long)r * 128 + c) = pk;
}

// ---------- generic 64x64-tile bf16 MFMA GEMM with fused epilogues ----------
template<int EPI, int KSTEPS>
__global__ __launch_bounds__(256) void gemm_k(const unsigned short* __restrict__ A,
                                              const unsigned short* __restrict__ Wt,
                                              const float* __restrict__ bias,
                                              void* __restrict__ out,
                                              const float* __restrict__ res) {
  const int K = KSTEPS * 32;
  int lane = threadIdx.x & 63;
  int wid  = threadIdx.x >> 6;
  int rowBase = blockIdx.x * 64 + wid * 16;
  int colBase = blockIdx.y * 64;
  int m  = lane & 15;
  int kg = lane >> 4;
  f32x4 acc[4] = {};
  const unsigned short* Ap = A  + (long)(rowBase + m) * K + kg * 8;
  const unsigned short* Bp = Wt + (long)(colBase + m) * K + kg * 8;
  for (int ks = 0; ks < KSTEPS; ks++) {
    bf16x8 a = ld8(Ap + ks * 32);
#pragma unroll
    for (int j = 0; j < 4; j++) {
      bf16x8 bb = ld8(Bp + j * 16 * K + ks * 32);
      acc[j] = __builtin_amdgcn_mfma_f32_16x16x32_bf16(a, bb, acc[j], 0, 0, 0);
    }
  }
#pragma unroll
  for (int j = 0; j < 4; j++) {
    int col = colBase + j * 16 + m;
    float bv = bias[col];
#pragma unroll
    for (int rgi = 0; rgi < 4; rgi++) {
      int row = rowBase + kg * 4 + rgi;
      float v = acc[j][rgi] + bv;
      if (EPI == 0) {
        ((unsigned short*)out)[(long)row * 384 + col] = f2bf(v);
      } else if (EPI == 1) {
        int t = win_row_to_token(row);
        ((float*)out)[(long)t * 128 + col] = res[(long)t * 128 + col] + v;
      } else if (EPI == 2) {
        float g = 0.5f * v * (1.0f + erff(v * 0.70710678118654752f));
        ((unsigned short*)out)[(long)row * 512 + col] = f2bf(g);
      } else {
        ((float*)out)[(long)row * 128 + col] = res[(long)row * 128 + col] + v;
      }
    }
  }
}

// ---------- MFMA window attention: 1 block/window, 1 wave/head, N pad 49->64 ----------
__global__ __launch_bounds__(256) void attn_mfma(const unsigned short* __restrict__ qkv,
                                                 const float* __restrict__ cls2,
                                                 unsigned short* __restrict__ out) {
  // XOR-swizzled LDS: col16 ^ ((row&7)<<3) keeps 16B alignment, kills conflicts
  __shared__ unsigned short vt[128 * 64];       // V^T [d][m], zero-padded m>=49
  __shared__ unsigned short pb[4][64 * 64];     // P per head, rows n, cols m
  int win = blockIdx.x;
  int tid = threadIdx.x;
  const unsigned short* qbase = qkv + (long)win * 49 * 384;

  // stage V^T (coalesced global read, swizzled LDS write)
  for (int i = tid; i < 49 * 128; i += 256) {
    int mm = i >> 7, d = i & 127;
    vt[d * 64 + (mm ^ ((d & 7) << 3))] = qbase[mm * 384 + 256 + d];
  }
  for (int i = tid; i < 128 * 15; i += 256) {   // zero pad rows m=49..63
    int d = i / 15, mm = 49 + i % 15;
    vt[d * 64 + (mm ^ ((d & 7) << 3))] = 0;
  }

  int h = tid >> 6, lane = tid & 63;
  int lr = lane & 15, g = lane >> 4;
  int w2 = win & 63;
  int cl = (((w2 >> 3) == 7) ? 2 : 0) + (((w2 & 7) == 7) ? 1 : 0);

  // Q/K fragments straight from global (16B/lane, coalesced)
  bf16x8 aq[4], bk[4];
  bf16x8 zf = {};
#pragma unroll
  for (int rt = 0; rt < 4; rt++)
    aq[rt] = ld8(qbase + (rt * 16 + lr) * 384 + h * 32 + g * 8);
#pragma unroll
  for (int ct = 0; ct < 4; ct++) {
    int mm = ct * 16 + lr;
    bk[ct] = (mm < 49) ? ld8(qbase + mm * 384 + 128 + h * 32 + g * 8) : zf;
  }
  f32x4 acc[4][4] = {};
#pragma unroll
  for (int rt = 0; rt < 4; rt++)
#pragma unroll
    for (int ct = 0; ct < 4; ct++)
      acc[rt][ct] = __builtin_amdgcn_mfma_f32_16x16x32_bf16(aq[rt], bk[ct], acc[rt][ct], 0, 0, 0);

  const float scale = 0.17677669529663687f;     // 32^-0.5
  const float* cb = cls2 + (long)(cl * 4 + h) * 16 * 256;
  unsigned short* P = pb[h];
#pragma unroll
  for (int rt = 0; rt < 4; rt++) {
    f32x4 c[4];
#pragma unroll
    for (int ct = 0; ct < 4; ct++)
      c[ct] = *reinterpret_cast<const f32x4*>(cb + (rt * 4 + ct) * 256 + lane * 4);
#pragma unroll
    for (int reg = 0; reg < 4; reg++) {
      float s0 = acc[rt][0][reg] * scale + c[0][reg];
      float s1 = acc[rt][1][reg] * scale + c[1][reg];
      float s2 = acc[rt][2][reg] * scale + c[2][reg];
      float s3 = acc[rt][3][reg] * scale + c[3][reg];
      float mx = fmaxf(fmaxf(s0, s1), fmaxf(s2, s3));
      mx = fmaxf(mx, __shfl_xor(mx, 1)); mx = fmaxf(mx, __shfl_xor(mx, 2));
      mx = fmaxf(mx, __shfl_xor(mx, 4)); mx = fmaxf(mx, __shfl_xor(mx, 8));
      float p0 = __expf(s0 - mx), p1 = __expf(s1 - mx);
      float p2 = __expf(s2 - mx), p3 = __expf(s3 - mx);
      float sum = p0 + p1 + p2 + p3;
      sum += __shfl_xor(sum, 1); sum += __shfl_xor(sum, 2);
      sum += __shfl_xor(sum, 4); sum += __shfl_xor(sum, 8);
      float inv = 1.f / sum;
      int n = rt * 16 + g * 4 + reg;
      int sw = (n & 7) << 3, rowb = n * 64;
      P[rowb + ((0 * 16 + lr) ^ sw)] = f2bf(p0 * inv);
      P[rowb + ((1 * 16 + lr) ^ sw)] = f2bf(p1 * inv);
      P[rowb + ((2 * 16 + lr) ^ sw)] = f2bf(p2 * inv);
      P[rowb + ((3 * 16 + lr) ^ sw)] = f2bf(p3 * inv);
    }
  }
  __syncthreads();   // vt ready (P is wave-private)

  // PV: O[n][d] = sum_m P[n][m] V[m][d]
  f32x4 o[4][2] = {};
  bf16x8 bv[2][2];
#pragma unroll
  for (int dt = 0; dt < 2; dt++)
#pragma unroll
    for (int ks = 0; ks < 2; ks++) {
      int d = h * 32 + dt * 16 + lr;
      bv[dt][ks] = ld8(&vt[d * 64 + ((ks * 32 + g * 8) ^ ((d & 7) << 3))]);
    }
#pragma unroll
  for (int rt = 0; rt < 4; rt++)
#pragma unroll
    for (int ks = 0; ks < 2; ks++) {
      int n = rt * 16 + lr;
      bf16x8 ap = ld8(&P[n * 64 + ((ks * 32 + g * 8) ^ ((n & 7) << 3))]);
#pragma unroll
      for (int dt = 0; dt < 2; dt++)
        o[rt][dt] = __builtin_amdgcn_mfma_f32_16x16x32_bf16(ap, bv[dt][ks], o[rt][dt], 0, 0, 0);
    }
#pragma unroll
  for (int rt = 0; rt < 4; rt++)
#pragma unroll
    for (int dt = 0; dt < 2; dt++)
#pragma unroll
      for (int reg = 0; reg < 4; reg++) {
        int n = rt * 16 + g * 4 + reg;
        if (n < 49)
          out[((long)win * 49 + n) * 128 + h * 32 + dt * 16 + lr] = f2bf(o[rt][dt][reg]);
      }
}

// ---------- launch ----------
extern "C" void kernel_launch(void* const* d_in, const int* in_sizes, int n_in,
                              void* d_out, int out_size, void* d_ws, size_t ws_size,
                              hipStream_t stream) {
  (void)in_sizes; (void)n_in; (void)out_size; (void)ws_size;
  const float* x      = (const float*)d_in[0];
  const float* qkv_w  = (const float*)d_in[1];
  const float* qkv_b  = (const float*)d_in[2];
  const float* proj_w = (const float*)d_in[3];
  const float* proj_b = (const float*)d_in[4];
  const float* rpb    = (const float*)d_in[5];
  const float* ln1_w  = (const float*)d_in[6];
  const float* ln1_b  = (const float*)d_in[7];
  const float* ln2_w  = (const float*)d_in[8];
  const float* ln2_b  = (const float*)d_in[9];
  const float* w1     = (const float*)d_in[10];
  const float* b1     = (const float*)d_in[11];
  const float* w2     = (const float*)d_in[12];
  const float* b2     = (const float*)d_in[13];

  char* ws = (char*)d_ws;
  // layout (bytes):
  //   0        : weights bf16 (393216)
  //   393216   : hb [T][128] bf16 (25690112)  -- later aliased by attnout, then by g
  //   26083328 : qkv [T][384] bf16 (77070336) -- later part of g
  //   103153664: out1 [T][128] f32 (51380224)
  //   154533888: mbuf [T][128] bf16 (25690112) -- cls2 (256KB) borrows this region
  //              (cls2 is dead before ln_kernel<false> writes mbuf)
  unsigned short* wts   = (unsigned short*)ws;
  unsigned short* hb    = (unsigned short*)(ws + 393216);
  unsigned short* qkv   = (unsigned short*)(ws + 26083328);
  unsigned short* attno = hb;                      // alias: hb dead after QKV gemm
  unsigned short* g     = hb;                      // alias: spans hb+qkv regions
  float*          out1  = (float*)(ws + 103153664);
  unsigned short* mbuf  = (unsigned short*)(ws + 154533888);
  float*          cls2  = (float*)(ws + 154533888);

  prep_weights<<<768, 256, 0, stream>>>(qkv_w, proj_w, w1, w2, wts);
  prep_cls<<<256, 256, 0, stream>>>(rpb, cls2);
  ln_kernel<true><<<T_TOK / 4, 256, 0, stream>>>(x, ln1_w, ln1_b, hb);
  gemm_k<0, 4><<<dim3(T_TOK / 64, 6), 256, 0, stream>>>(hb, wts, qkv_b, qkv, nullptr);
  attn_mfma<<<NWIN, 256, 0, stream>>>(qkv, cls2, attno);
  gemm_k<1, 4><<<dim3(T_TOK / 64, 2), 256, 0, stream>>>(attno, wts + 49152, proj_b, out1, x);
  ln_kernel<false><<<T_TOK / 4, 256, 0, stream>>>(out1, ln2_w, ln2_b, mbuf);
  gemm_k<2, 4><<<dim3(T_TOK / 64, 8), 256, 0, stream>>>(mbuf, wts + 65536, b1, g, nullptr);
  gemm_k<3, 16><<<dim3(T_TOK / 64, 2), 256, 0, stream>>>(g, wts + 131072, b2, (float*)d_out, out1);
}

// Round 3
// 336.670 us; speedup vs baseline: 2.3013x; 1.3404x over previous
//
#include <hip/hip_runtime.h>
#include <hip/hip_bf16.h>

// ---------- constants ----------
#define T_TOK   100352      // 32 * 3136 tokens
#define NWIN    2048        // 32 * 64 windows
#define EPS_LN  1e-5f

typedef __attribute__((ext_vector_type(8))) short bf16x8;
typedef __attribute__((ext_vector_type(4))) float f32x4;

// ---------- helpers ----------
__device__ inline float bf2f(unsigned short u) {
  union { unsigned int i; float f; } c; c.i = ((unsigned int)u) << 16; return c.f;
}
__device__ inline unsigned short f2bf(float f) {
  union { float f; unsigned int i; } c; c.f = f;
  unsigned int x = c.i;
  x += 0x7fffu + ((x >> 16) & 1u);   // round-to-nearest-even
  return (unsigned short)(x >> 16);
}
__device__ inline bf16x8 ld8(const unsigned short* p) {
  return *reinterpret_cast<const bf16x8*>(p);
}

// window-ordered row r (win*49 + n) -> token index (b*3136 + l)
__device__ inline int win_row_to_token(int r) {
  int win = r / 49, n = r % 49;
  int b  = win >> 6, w2 = win & 63;
  int wi = w2 >> 3,  wj = w2 & 7;
  int rr = n / 7,    cc = n % 7;
  return b * 3136 + (wi * 7 + rr) * 56 + (wj * 7 + cc);
}

// ---------- kernel 0: weights -> bf16, transposed to [N][K] ----------
__global__ void prep_weights(const float* __restrict__ qkv_w,
                             const float* __restrict__ proj_w,
                             const float* __restrict__ w1,
                             const float* __restrict__ w2,
                             unsigned short* __restrict__ wts) {
  int i = blockIdx.x * 256 + threadIdx.x;
  unsigned short* qkvt  = wts;            // [384][128]
  unsigned short* projt = wts + 49152;    // [128][128]
  unsigned short* w1t   = wts + 65536;    // [512][128]
  unsigned short* w2t   = wts + 131072;   // [128][512]
  if (i < 49152) {
    int n = i >> 7, k = i & 127; qkvt[i] = f2bf(qkv_w[k * 384 + n]);
  } else if (i < 65536) {
    int e = i - 49152; int n = e >> 7, k = e & 127; projt[e] = f2bf(proj_w[k * 128 + n]);
  } else if (i < 131072) {
    int e = i - 65536; int n = e >> 7, k = e & 127; w1t[e] = f2bf(w1[k * 512 + n]);
  } else if (i < 196608) {
    int e = i - 131072; int n = e >> 9, k = e & 511; w2t[e] = f2bf(w2[k * 128 + n]);
  }
}

// ---------- kernel 0b: bias+mask table in C-fragment order ----------
// cls2[cl][h][rt][ct][lane][reg] : 4*4*4*4*64*4 floats = 256 KB
__global__ void prep_cls(const float* __restrict__ rpb, float* __restrict__ cls2) {
  int i = blockIdx.x * 256 + threadIdx.x;          // 65536 total
  int reg = i & 3, lane = (i >> 2) & 63, ct = (i >> 8) & 3, rt = (i >> 10) & 3,
      h = (i >> 12) & 3, cl = (i >> 14) & 3;
  int n = rt * 16 + ((lane >> 4) << 2) + reg;
  int m = ct * 16 + (lane & 15);
  float v = -30000.f;                               // padding mask (finite, exp->0)
  if (n < 49 && m < 49) {
    int nr = n / 7, nc = n % 7, mr = m / 7, mc = m % 7;
    v = rpb[((nr - mr + 6) * 13 + (nc - mc + 6)) * 4 + h];
    int regn = ((cl & 2) ? (nr < 4 ? 3 : 6) : 0) + ((cl & 1) ? (nc < 4 ? 1 : 2) : 0);
    int regm = ((cl & 2) ? (mr < 4 ? 3 : 6) : 0) + ((cl & 1) ? (mc < 4 ? 1 : 2) : 0);
    if (regn != regm) v -= 100.f;
  }
  cls2[i] = v;
}

// ---------- layernorm (optionally gathering window-partition order) ----------
template<bool WINMAP>
__global__ __launch_bounds__(256) void ln_kernel(const float* __restrict__ x,
                                                 const float* __restrict__ w,
                                                 const float* __restrict__ b,
                                                 unsigned short* __restrict__ out) {
  int r    = blockIdx.x * 4 + (threadIdx.x >> 6);
  int lane = threadIdx.x & 63;
  int src  = WINMAP ? win_row_to_token(r) : r;
  float2 v = *reinterpret_cast<const float2*>(x + (long)src * 128 + lane * 2);
  float s  = v.x + v.y;
  float s2 = v.x * v.x + v.y * v.y;
#pragma unroll
  for (int off = 32; off; off >>= 1) {
    s  += __shfl_xor(s,  off);
    s2 += __shfl_xor(s2, off);
  }
  float mu  = s * (1.f / 128.f);
  float var = s2 * (1.f / 128.f) - mu * mu;
  float inv = rsqrtf(var + EPS_LN);
  int c = lane * 2;
  float2 wv = *reinterpret_cast<const float2*>(w + c);
  float2 bv = *reinterpret_cast<const float2*>(b + c);
  float y0 = (v.x - mu) * inv * wv.x + bv.x;
  float y1 = (v.y - mu) * inv * wv.y + bv.y;
  unsigned int pk = ((unsigned int)f2bf(y1) << 16) | (unsigned int)f2bf(y0);
  *reinterpret_cast<unsigned int*>(out + (long)r * 128 + c) = pk;
}

// ---------- 128x64-tile bf16 MFMA GEMM, XCD-swizzled 1-D grid ----------
// A: [M][K] bf16 row-major.  Wt: [N][K] bf16 (transposed weights).
// Wave computes 32 rows x 64 cols (acc[2][4]); block = 4 waves = 128 rows.
// EPI 0: qkv -> bf16 out (stride 384) +bias
// EPI 1: proj -> f32 out1[t] = res[t] + acc + bias (window-reverse map)
// EPI 2: mlp1 -> bf16 out (stride 512), gelu(acc+bias)  [tanh-form]
// EPI 3: mlp2 -> f32 d_out[r] = res[r] + acc + bias
template<int EPI, int KSTEPS, int NBN>
__global__ __launch_bounds__(256) void gemm_k(const unsigned short* __restrict__ A,
                                              const unsigned short* __restrict__ Wt,
                                              const float* __restrict__ bias,
                                              void* __restrict__ out,
                                              const float* __restrict__ res) {
  const int K = KSTEPS * 32;
  // bijective XCD swizzle: each XCD gets a contiguous run of m-panels,
  // with all NBN col-tiles of a panel adjacent in dispatch order.
  int flat  = blockIdx.x;
  int chunk = gridDim.x >> 3;
  int swz   = (flat & 7) * chunk + (flat >> 3);
  int ntile = swz % NBN, mpan = swz / NBN;

  int lane = threadIdx.x & 63;
  int wid  = threadIdx.x >> 6;
  int rowBase = mpan * 128 + wid * 32;
  int colBase = ntile * 64;
  int m  = lane & 15;
  int kg = lane >> 4;
  f32x4 acc[2][4] = {};
  const unsigned short* Ap = A  + (long)(rowBase + m) * K + kg * 8;
  const unsigned short* Bp = Wt + (long)(colBase + m) * K + kg * 8;
#pragma unroll 4
  for (int ks = 0; ks < KSTEPS; ks++) {
    bf16x8 b0 = ld8(Bp + 0 * 16 * K + ks * 32);
    bf16x8 b1 = ld8(Bp + 1 * 16 * K + ks * 32);
    bf16x8 b2 = ld8(Bp + 2 * 16 * K + ks * 32);
    bf16x8 b3 = ld8(Bp + 3 * 16 * K + ks * 32);
    bf16x8 a0 = ld8(Ap + ks * 32);
    bf16x8 a1 = ld8(Ap + (long)16 * K + ks * 32);
    acc[0][0] = __builtin_amdgcn_mfma_f32_16x16x32_bf16(a0, b0, acc[0][0], 0, 0, 0);
    acc[0][1] = __builtin_amdgcn_mfma_f32_16x16x32_bf16(a0, b1, acc[0][1], 0, 0, 0);
    acc[0][2] = __builtin_amdgcn_mfma_f32_16x16x32_bf16(a0, b2, acc[0][2], 0, 0, 0);
    acc[0][3] = __builtin_amdgcn_mfma_f32_16x16x32_bf16(a0, b3, acc[0][3], 0, 0, 0);
    acc[1][0] = __builtin_amdgcn_mfma_f32_16x16x32_bf16(a1, b0, acc[1][0], 0, 0, 0);
    acc[1][1] = __builtin_amdgcn_mfma_f32_16x16x32_bf16(a1, b1, acc[1][1], 0, 0, 0);
    acc[1][2] = __builtin_amdgcn_mfma_f32_16x16x32_bf16(a1, b2, acc[1][2], 0, 0, 0);
    acc[1][3] = __builtin_amdgcn_mfma_f32_16x16x32_bf16(a1, b3, acc[1][3], 0, 0, 0);
  }
#pragma unroll
  for (int mt = 0; mt < 2; mt++) {
#pragma unroll
    for (int rgi = 0; rgi < 4; rgi++) {
      int row = rowBase + mt * 16 + kg * 4 + rgi;
      int t = (EPI == 1) ? win_row_to_token(row) : row;
#pragma unroll
      for (int j = 0; j < 4; j++) {
        int col = colBase + j * 16 + m;
        float v = acc[mt][j][rgi] + bias[col];
        if (EPI == 0) {
          ((unsigned short*)out)[(long)row * 384 + col] = f2bf(v);
        } else if (EPI == 1) {
          ((float*)out)[(long)t * 128 + col] = res[(long)t * 128 + col] + v;
        } else if (EPI == 2) {
          float u = v * (1.0f + 0.044715f * v * v);
          float g = v / (1.0f + __expf(-1.5957691216f * u));
          ((unsigned short*)out)[(long)row * 512 + col] = f2bf(g);
        } else {
          ((float*)out)[(long)row * 128 + col] = res[(long)row * 128 + col] + v;
        }
      }
    }
  }
}

// ---------- MFMA window attention: 1 block/window, 1 wave/head, N pad 49->64 ----------
__global__ __launch_bounds__(256) void attn_mfma(const unsigned short* __restrict__ qkv,
                                                 const float* __restrict__ cls2,
                                                 unsigned short* __restrict__ out) {
  // XOR-swizzled LDS: col16 ^ ((row&7)<<3) keeps 16B alignment, kills conflicts
  __shared__ unsigned short vt[128 * 64];       // V^T [d][m], zero-padded m>=49
  __shared__ unsigned short pb[4][64 * 64];     // P per head, rows n, cols m
  int win = blockIdx.x;
  int tid = threadIdx.x;
  const unsigned short* qbase = qkv + (long)win * 49 * 384;

  // stage V^T (coalesced global read, swizzled LDS write)
  for (int i = tid; i < 49 * 128; i += 256) {
    int mm = i >> 7, d = i & 127;
    vt[d * 64 + (mm ^ ((d & 7) << 3))] = qbase[mm * 384 + 256 + d];
  }
  for (int i = tid; i < 128 * 15; i += 256) {   // zero pad rows m=49..63
    int d = i / 15, mm = 49 + i % 15;
    vt[d * 64 + (mm ^ ((d & 7) << 3))] = 0;
  }

  int h = tid >> 6, lane = tid & 63;
  int lr = lane & 15, g = lane >> 4;
  int w2 = win & 63;
  int cl = (((w2 >> 3) == 7) ? 2 : 0) + (((w2 & 7) == 7) ? 1 : 0);

  // Q/K fragments straight from global (16B/lane, coalesced)
  bf16x8 aq[4], bk[4];
  bf16x8 zf = {};
#pragma unroll
  for (int rt = 0; rt < 4; rt++)
    aq[rt] = ld8(qbase + (rt * 16 + lr) * 384 + h * 32 + g * 8);
#pragma unroll
  for (int ct = 0; ct < 4; ct++) {
    int mm = ct * 16 + lr;
    bk[ct] = (mm < 49) ? ld8(qbase + mm * 384 + 128 + h * 32 + g * 8) : zf;
  }
  f32x4 acc[4][4] = {};
#pragma unroll
  for (int rt = 0; rt < 4; rt++)
#pragma unroll
    for (int ct = 0; ct < 4; ct++)
      acc[rt][ct] = __builtin_amdgcn_mfma_f32_16x16x32_bf16(aq[rt], bk[ct], acc[rt][ct], 0, 0, 0);

  const float scale = 0.17677669529663687f;     // 32^-0.5
  const float* cb = cls2 + (long)(cl * 4 + h) * 16 * 256;
  unsigned short* P = pb[h];
#pragma unroll
  for (int rt = 0; rt < 4; rt++) {
    f32x4 c[4];
#pragma unroll
    for (int ct = 0; ct < 4; ct++)
      c[ct] = *reinterpret_cast<const f32x4*>(cb + (rt * 4 + ct) * 256 + lane * 4);
#pragma unroll
    for (int reg = 0; reg < 4; reg++) {
      float s0 = acc[rt][0][reg] * scale + c[0][reg];
      float s1 = acc[rt][1][reg] * scale + c[1][reg];
      float s2 = acc[rt][2][reg] * scale + c[2][reg];
      float s3 = acc[rt][3][reg] * scale + c[3][reg];
      float mx = fmaxf(fmaxf(s0, s1), fmaxf(s2, s3));
      mx = fmaxf(mx, __shfl_xor(mx, 1)); mx = fmaxf(mx, __shfl_xor(mx, 2));
      mx = fmaxf(mx, __shfl_xor(mx, 4)); mx = fmaxf(mx, __shfl_xor(mx, 8));
      float p0 = __expf(s0 - mx), p1 = __expf(s1 - mx);
      float p2 = __expf(s2 - mx), p3 = __expf(s3 - mx);
      float sum = p0 + p1 + p2 + p3;
      sum += __shfl_xor(sum, 1); sum += __shfl_xor(sum, 2);
      sum += __shfl_xor(sum, 4); sum += __shfl_xor(sum, 8);
      float inv = 1.f / sum;
      int n = rt * 16 + g * 4 + reg;
      int sw = (n & 7) << 3, rowb = n * 64;
      P[rowb + ((0 * 16 + lr) ^ sw)] = f2bf(p0 * inv);
      P[rowb + ((1 * 16 + lr) ^ sw)] = f2bf(p1 * inv);
      P[rowb + ((2 * 16 + lr) ^ sw)] = f2bf(p2 * inv);
      P[rowb + ((3 * 16 + lr) ^ sw)] = f2bf(p3 * inv);
    }
  }
  __syncthreads();   // vt ready (P is wave-private)

  // PV: O[n][d] = sum_m P[n][m] V[m][d]
  f32x4 o[4][2] = {};
  bf16x8 bv[2][2];
#pragma unroll
  for (int dt = 0; dt < 2; dt++)
#pragma unroll
    for (int ks = 0; ks < 2; ks++) {
      int d = h * 32 + dt * 16 + lr;
      bv[dt][ks] = ld8(&vt[d * 64 + ((ks * 32 + g * 8) ^ ((d & 7) << 3))]);
    }
#pragma unroll
  for (int rt = 0; rt < 4; rt++)
#pragma unroll
    for (int ks = 0; ks < 2; ks++) {
      int n = rt * 16 + lr;
      bf16x8 ap = ld8(&P[n * 64 + ((ks * 32 + g * 8) ^ ((n & 7) << 3))]);
#pragma unroll
      for (int dt = 0; dt < 2; dt++)
        o[rt][dt] = __builtin_amdgcn_mfma_f32_16x16x32_bf16(ap, bv[dt][ks], o[rt][dt], 0, 0, 0);
    }
#pragma unroll
  for (int rt = 0; rt < 4; rt++)
#pragma unroll
    for (int dt = 0; dt < 2; dt++)
#pragma unroll
      for (int reg = 0; reg < 4; reg++) {
        int n = rt * 16 + g * 4 + reg;
        if (n < 49)
          out[((long)win * 49 + n) * 128 + h * 32 + dt * 16 + lr] = f2bf(o[rt][dt][reg]);
      }
}

// ---------- launch ----------
extern "C" void kernel_launch(void* const* d_in, const int* in_sizes, int n_in,
                              void* d_out, int out_size, void* d_ws, size_t ws_size,
                              hipStream_t stream) {
  (void)in_sizes; (void)n_in; (void)out_size; (void)ws_size;
  const float* x      = (const float*)d_in[0];
  const float* qkv_w  = (const float*)d_in[1];
  const float* qkv_b  = (const float*)d_in[2];
  const float* proj_w = (const float*)d_in[3];
  const float* proj_b = (const float*)d_in[4];
  const float* rpb    = (const float*)d_in[5];
  const float* ln1_w  = (const float*)d_in[6];
  const float* ln1_b  = (const float*)d_in[7];
  const float* ln2_w  = (const float*)d_in[8];
  const float* ln2_b  = (const float*)d_in[9];
  const float* w1     = (const float*)d_in[10];
  const float* b1     = (const float*)d_in[11];
  const float* w2     = (const float*)d_in[12];
  const float* b2     = (const float*)d_in[13];

  char* ws = (char*)d_ws;
  // layout (bytes):
  //   0        : weights bf16 (393216)
  //   393216   : hb [T][128] bf16 (25690112)  -- later aliased by attnout, then by g
  //   26083328 : qkv [T][384] bf16 (77070336) -- later part of g
  //   103153664: out1 [T][128] f32 (51380224)
  //   154533888: mbuf [T][128] bf16 (25690112) -- cls2 (256KB) borrows this region
  //              (cls2 is dead before ln_kernel<false> writes mbuf)
  unsigned short* wts   = (unsigned short*)ws;
  unsigned short* hb    = (unsigned short*)(ws + 393216);
  unsigned short* qkv   = (unsigned short*)(ws + 26083328);
  unsigned short* attno = hb;                      // alias: hb dead after QKV gemm
  unsigned short* g     = hb;                      // alias: spans hb+qkv regions
  float*          out1  = (float*)(ws + 103153664);
  unsigned short* mbuf  = (unsigned short*)(ws + 154533888);
  float*          cls2  = (float*)(ws + 154533888);

  const int MP = T_TOK / 128;   // 784 m-panels

  prep_weights<<<768, 256, 0, stream>>>(qkv_w, proj_w, w1, w2, wts);
  prep_cls<<<256, 256, 0, stream>>>(rpb, cls2);
  ln_kernel<true><<<T_TOK / 4, 256, 0, stream>>>(x, ln1_w, ln1_b, hb);
  gemm_k<0, 4, 6><<<MP * 6, 256, 0, stream>>>(hb, wts, qkv_b, qkv, nullptr);
  attn_mfma<<<NWIN, 256, 0, stream>>>(qkv, cls2, attno);
  gemm_k<1, 4, 2><<<MP * 2, 256, 0, stream>>>(attno, wts + 49152, proj_b, out1, x);
  ln_kernel<false><<<T_TOK / 4, 256, 0, stream>>>(out1, ln2_w, ln2_b, mbuf);
  gemm_k<2, 4, 8><<<MP * 8, 256, 0, stream>>>(mbuf, wts + 65536, b1, g, nullptr);
  gemm_k<3, 16, 2><<<MP * 2, 256, 0, stream>>>(g, wts + 131072, b2, (float*)d_out, out1);
}

// Round 6
// 279.391 us; speedup vs baseline: 2.7731x; 1.2050x over previous
//
#include <hip/hip_runtime.h>
#include <hip/hip_bf16.h>

// ---------- constants ----------
#define T_TOK   100352      // 32 * 3136 tokens
#define NWIN    2048        // 32 * 64 windows
#define EPS_LN  1e-5f

typedef __attribute__((ext_vector_type(8))) short bf16x8;
typedef __attribute__((ext_vector_type(4))) float f32x4;

// ---------- helpers ----------
__device__ inline unsigned short f2bf(float f) {
  union { float f; unsigned int i; } c; c.f = f;
  unsigned int x = c.i;
  x += 0x7fffu + ((x >> 16) & 1u);   // round-to-nearest-even
  return (unsigned short)(x >> 16);
}
__device__ inline bf16x8 ld8(const unsigned short* p) {
  return *reinterpret_cast<const bf16x8*>(p);
}

// window-ordered row r (win*49 + n) -> token index (b*3136 + l)
__device__ inline int win_row_to_token(int r) {
  int win = r / 49, n = r % 49;
  int b  = win >> 6, w2 = win & 63;
  int wi = w2 >> 3,  wj = w2 & 7;
  int rr = n / 7,    cc = n % 7;
  return b * 3136 + (wi * 7 + rr) * 56 + (wj * 7 + cc);
}

// ---------- kernel 0: weights -> bf16, transposed to [N][K] ----------
__global__ void prep_weights(const float* __restrict__ qkv_w,
                             const float* __restrict__ proj_w,
                             const float* __restrict__ w1,
                             const float* __restrict__ w2,
                             unsigned short* __restrict__ wts) {
  int i = blockIdx.x * 256 + threadIdx.x;
  unsigned short* qkvt  = wts;            // [384][128]
  unsigned short* projt = wts + 49152;    // [128][128]
  unsigned short* w1t   = wts + 65536;    // [512][128]
  unsigned short* w2t   = wts + 131072;   // [128][512]
  if (i < 49152) {
    int n = i >> 7, k = i & 127; qkvt[i] = f2bf(qkv_w[k * 384 + n]);
  } else if (i < 65536) {
    int e = i - 49152; int n = e >> 7, k = e & 127; projt[e] = f2bf(proj_w[k * 128 + n]);
  } else if (i < 131072) {
    int e = i - 65536; int n = e >> 7, k = e & 127; w1t[e] = f2bf(w1[k * 512 + n]);
  } else if (i < 196608) {
    int e = i - 131072; int n = e >> 9, k = e & 511; w2t[e] = f2bf(w2[k * 128 + n]);
  }
}

// ---------- kernel 0b: bias+mask table in C-fragment order ----------
// cls2[cl][h][rt][ct][lane][reg] : 4*4*4*4*64*4 floats = 256 KB
__global__ void prep_cls(const float* __restrict__ rpb, float* __restrict__ cls2) {
  int i = blockIdx.x * 256 + threadIdx.x;          // 65536 total
  int reg = i & 3, lane = (i >> 2) & 63, ct = (i >> 8) & 3, rt = (i >> 10) & 3,
      h = (i >> 12) & 3, cl = (i >> 14) & 3;
  int n = rt * 16 + ((lane >> 4) << 2) + reg;
  int m = ct * 16 + (lane & 15);
  float v = -30000.f;                               // padding mask (finite, exp->0)
  if (n < 49 && m < 49) {
    int nr = n / 7, nc = n % 7, mr = m / 7, mc = m % 7;
    v = rpb[((nr - mr + 6) * 13 + (nc - mc + 6)) * 4 + h];
    int regn = ((cl & 2) ? (nr < 4 ? 3 : 6) : 0) + ((cl & 1) ? (nc < 4 ? 1 : 2) : 0);
    int regm = ((cl & 2) ? (mr < 4 ? 3 : 6) : 0) + ((cl & 1) ? (mc < 4 ? 1 : 2) : 0);
    if (regn != regm) v -= 100.f;
  }
  cls2[i] = v;
}

// ---------- layernorm (optionally gathering window-partition order) ----------
template<bool WINMAP>
__global__ __launch_bounds__(256) void ln_kernel(const float* __restrict__ x,
                                                 const float* __restrict__ w,
                                                 const float* __restrict__ b,
                                                 unsigned short* __restrict__ out) {
  int r    = blockIdx.x * 4 + (threadIdx.x >> 6);
  int lane = threadIdx.x & 63;
  int src  = WINMAP ? win_row_to_token(r) : r;
  float2 v = *reinterpret_cast<const float2*>(x + (long)src * 128 + lane * 2);
  float s  = v.x + v.y;
  float s2 = v.x * v.x + v.y * v.y;
#pragma unroll
  for (int off = 32; off; off >>= 1) {
    s  += __shfl_xor(s,  off);
    s2 += __shfl_xor(s2, off);
  }
  float mu  = s * (1.f / 128.f);
  float var = s2 * (1.f / 128.f) - mu * mu;
  float inv = rsqrtf(var + EPS_LN);
  int c = lane * 2;
  float2 wv = *reinterpret_cast<const float2*>(w + c);
  float2 bv = *reinterpret_cast<const float2*>(b + c);
  float y0 = (v.x - mu) * inv * wv.x + bv.x;
  float y1 = (v.y - mu) * inv * wv.y + bv.y;
  unsigned int pk = ((unsigned int)f2bf(y1) << 16) | (unsigned int)f2bf(y0);
  *reinterpret_cast<unsigned int*>(out + (long)r * 128 + c) = pk;
}

// ---------- 128x64-tile bf16 MFMA GEMM, XCD-swizzled 1-D grid ----------
// EPI 0: qkv -> bf16 out (stride 384) +bias
// EPI 1: proj -> f32 out1[t] = res[t] + acc + bias (window-reverse map)
template<int EPI, int KSTEPS, int NBN>
__global__ __launch_bounds__(256) void gemm_k(const unsigned short* __restrict__ A,
                                              const unsigned short* __restrict__ Wt,
                                              const float* __restrict__ bias,
                                              void* __restrict__ out,
                                              const float* __restrict__ res) {
  const int K = KSTEPS * 32;
  int flat  = blockIdx.x;
  int chunk = gridDim.x >> 3;
  int swz   = (flat & 7) * chunk + (flat >> 3);
  int ntile = swz % NBN, mpan = swz / NBN;

  int lane = threadIdx.x & 63;
  int wid  = threadIdx.x >> 6;
  int rowBase = mpan * 128 + wid * 32;
  int colBase = ntile * 64;
  int m  = lane & 15;
  int kg = lane >> 4;
  f32x4 acc[2][4] = {};
  const unsigned short* Ap = A  + (long)(rowBase + m) * K + kg * 8;
  const unsigned short* Bp = Wt + (long)(colBase + m) * K + kg * 8;
#pragma unroll 4
  for (int ks = 0; ks < KSTEPS; ks++) {
    bf16x8 b0 = ld8(Bp + 0 * 16 * K + ks * 32);
    bf16x8 b1 = ld8(Bp + 1 * 16 * K + ks * 32);
    bf16x8 b2 = ld8(Bp + 2 * 16 * K + ks * 32);
    bf16x8 b3 = ld8(Bp + 3 * 16 * K + ks * 32);
    bf16x8 a0 = ld8(Ap + ks * 32);
    bf16x8 a1 = ld8(Ap + (long)16 * K + ks * 32);
    acc[0][0] = __builtin_amdgcn_mfma_f32_16x16x32_bf16(a0, b0, acc[0][0], 0, 0, 0);
    acc[0][1] = __builtin_amdgcn_mfma_f32_16x16x32_bf16(a0, b1, acc[0][1], 0, 0, 0);
    acc[0][2] = __builtin_amdgcn_mfma_f32_16x16x32_bf16(a0, b2, acc[0][2], 0, 0, 0);
    acc[0][3] = __builtin_amdgcn_mfma_f32_16x16x32_bf16(a0, b3, acc[0][3], 0, 0, 0);
    acc[1][0] = __builtin_amdgcn_mfma_f32_16x16x32_bf16(a1, b0, acc[1][0], 0, 0, 0);
    acc[1][1] = __builtin_amdgcn_mfma_f32_16x16x32_bf16(a1, b1, acc[1][1], 0, 0, 0);
    acc[1][2] = __builtin_amdgcn_mfma_f32_16x16x32_bf16(a1, b2, acc[1][2], 0, 0, 0);
    acc[1][3] = __builtin_amdgcn_mfma_f32_16x16x32_bf16(a1, b3, acc[1][3], 0, 0, 0);
  }
#pragma unroll
  for (int mt = 0; mt < 2; mt++) {
#pragma unroll
    for (int rgi = 0; rgi < 4; rgi++) {
      int row = rowBase + mt * 16 + kg * 4 + rgi;
      int t = (EPI == 1) ? win_row_to_token(row) : row;
#pragma unroll
      for (int j = 0; j < 4; j++) {
        int col = colBase + j * 16 + m;
        float v = acc[mt][j][rgi] + bias[col];
        if (EPI == 0) {
          ((unsigned short*)out)[(long)row * 384 + col] = f2bf(v);
        } else {
          ((float*)out)[(long)t * 128 + col] = res[(long)t * 128 + col] + v;
        }
      }
    }
  }
}

// ---------- MFMA window attention (round-3 verbatim, passing) ----------
__global__ __launch_bounds__(256) void attn_mfma(const unsigned short* __restrict__ qkv,
                                                 const float* __restrict__ cls2,
                                                 unsigned short* __restrict__ out) {
  __shared__ unsigned short vt[128 * 64];       // V^T [d][m], zero-padded m>=49
  __shared__ unsigned short pb[4][64 * 64];     // P per head, rows n, cols m
  int win = blockIdx.x;
  int tid = threadIdx.x;
  const unsigned short* qbase = qkv + (long)win * 49 * 384;

  for (int i = tid; i < 49 * 128; i += 256) {
    int mm = i >> 7, d = i & 127;
    vt[d * 64 + (mm ^ ((d & 7) << 3))] = qbase[mm * 384 + 256 + d];
  }
  for (int i = tid; i < 128 * 15; i += 256) {   // zero pad rows m=49..63
    int d = i / 15, mm = 49 + i % 15;
    vt[d * 64 + (mm ^ ((d & 7) << 3))] = 0;
  }

  int h = tid >> 6, lane = tid & 63;
  int lr = lane & 15, g = lane >> 4;
  int w2 = win & 63;
  int cl = (((w2 >> 3) == 7) ? 2 : 0) + (((w2 & 7) == 7) ? 1 : 0);

  bf16x8 aq[4], bk[4];
  bf16x8 zf = {};
#pragma unroll
  for (int rt = 0; rt < 4; rt++)
    aq[rt] = ld8(qbase + (rt * 16 + lr) * 384 + h * 32 + g * 8);
#pragma unroll
  for (int ct = 0; ct < 4; ct++) {
    int mm = ct * 16 + lr;
    bk[ct] = (mm < 49) ? ld8(qbase + mm * 384 + 128 + h * 32 + g * 8) : zf;
  }
  f32x4 acc[4][4] = {};
#pragma unroll
  for (int rt = 0; rt < 4; rt++)
#pragma unroll
    for (int ct = 0; ct < 4; ct++)
      acc[rt][ct] = __builtin_amdgcn_mfma_f32_16x16x32_bf16(aq[rt], bk[ct], acc[rt][ct], 0, 0, 0);

  const float scale = 0.17677669529663687f;     // 32^-0.5
  const float* cb = cls2 + (long)(cl * 4 + h) * 16 * 256;
  unsigned short* P = pb[h];
#pragma unroll
  for (int rt = 0; rt < 4; rt++) {
    f32x4 c[4];
#pragma unroll
    for (int ct = 0; ct < 4; ct++)
      c[ct] = *reinterpret_cast<const f32x4*>(cb + (rt * 4 + ct) * 256 + lane * 4);
#pragma unroll
    for (int reg = 0; reg < 4; reg++) {
      float s0 = acc[rt][0][reg] * scale + c[0][reg];
      float s1 = acc[rt][1][reg] * scale + c[1][reg];
      float s2 = acc[rt][2][reg] * scale + c[2][reg];
      float s3 = acc[rt][3][reg] * scale + c[3][reg];
      float mx = fmaxf(fmaxf(s0, s1), fmaxf(s2, s3));
      mx = fmaxf(mx, __shfl_xor(mx, 1)); mx = fmaxf(mx, __shfl_xor(mx, 2));
      mx = fmaxf(mx, __shfl_xor(mx, 4)); mx = fmaxf(mx, __shfl_xor(mx, 8));
      float p0 = __expf(s0 - mx), p1 = __expf(s1 - mx);
      float p2 = __expf(s2 - mx), p3 = __expf(s3 - mx);
      float sum = p0 + p1 + p2 + p3;
      sum += __shfl_xor(sum, 1); sum += __shfl_xor(sum, 2);
      sum += __shfl_xor(sum, 4); sum += __shfl_xor(sum, 8);
      float inv = 1.f / sum;
      int n = rt * 16 + g * 4 + reg;
      int sw = (n & 7) << 3, rowb = n * 64;
      P[rowb + ((0 * 16 + lr) ^ sw)] = f2bf(p0 * inv);
      P[rowb + ((1 * 16 + lr) ^ sw)] = f2bf(p1 * inv);
      P[rowb + ((2 * 16 + lr) ^ sw)] = f2bf(p2 * inv);
      P[rowb + ((3 * 16 + lr) ^ sw)] = f2bf(p3 * inv);
    }
  }
  __syncthreads();   // vt ready (P is wave-private)

  f32x4 o[4][2] = {};
  bf16x8 bv[2][2];
#pragma unroll
  for (int dt = 0; dt < 2; dt++)
#pragma unroll
    for (int ks = 0; ks < 2; ks++) {
      int d = h * 32 + dt * 16 + lr;
      bv[dt][ks] = ld8(&vt[d * 64 + ((ks * 32 + g * 8) ^ ((d & 7) << 3))]);
    }
#pragma unroll
  for (int rt = 0; rt < 4; rt++)
#pragma unroll
    for (int ks = 0; ks < 2; ks++) {
      int n = rt * 16 + lr;
      bf16x8 ap = ld8(&P[n * 64 + ((ks * 32 + g * 8) ^ ((n & 7) << 3))]);
#pragma unroll
      for (int dt = 0; dt < 2; dt++)
        o[rt][dt] = __builtin_amdgcn_mfma_f32_16x16x32_bf16(ap, bv[dt][ks], o[rt][dt], 0, 0, 0);
    }
#pragma unroll
  for (int rt = 0; rt < 4; rt++)
#pragma unroll
    for (int dt = 0; dt < 2; dt++)
#pragma unroll
      for (int reg = 0; reg < 4; reg++) {
        int n = rt * 16 + g * 4 + reg;
        if (n < 49)
          out[((long)win * 49 + n) * 128 + h * 32 + dt * 16 + lr] = f2bf(o[rt][dt][reg]);
      }
}

// ---------- fused MLP v2: LN2 + MLP1 + GELU + MLP2 + residual ----------
// DEFENSIVE variant: no XOR swizzles (padded row strides, 16B-aligned,
// 2-way-conflict-free), 512 threads / 8 waves, 1 block per CU (82 KB LDS).
// lnm stride 136 (272 B = 17*16), gel stride 520 (1040 B = 65*16).
__global__ __launch_bounds__(512, 1) void mlp_fused(
    const float* __restrict__ out1,
    const unsigned short* __restrict__ w1t,   // [512][128]
    const float* __restrict__ b1,
    const unsigned short* __restrict__ w2t,   // [128][512]
    const float* __restrict__ b2,
    const float* __restrict__ ln2w,
    const float* __restrict__ ln2b,
    float* __restrict__ dout) {
  __shared__ unsigned short lnm[64 * 136];
  __shared__ unsigned short gel[64 * 520];
  long rowbase = (long)blockIdx.x * 64;
  int tid = threadIdx.x, w = tid >> 6, lane = tid & 63, lr = lane & 15, g = lane >> 4;

  // ---- phase 0: LN2, 8 rows per wave ----
  {
    int c = lane * 2;
    float2 wv = *(const float2*)(ln2w + c);
    float2 bv = *(const float2*)(ln2b + c);
    for (int n = w; n < 64; n += 8) {
      float2 v = *(const float2*)(out1 + (rowbase + n) * 128 + c);
      float s = v.x + v.y, s2 = v.x * v.x + v.y * v.y;
#pragma unroll
      for (int off = 32; off; off >>= 1) { s += __shfl_xor(s, off); s2 += __shfl_xor(s2, off); }
      float mu  = s * (1.f / 128.f);
      float inv = rsqrtf(s2 * (1.f / 128.f) - mu * mu + EPS_LN);
      float y0 = (v.x - mu) * inv * wv.x + bv.x;
      float y1 = (v.y - mu) * inv * wv.y + bv.y;
      unsigned int pk = ((unsigned int)f2bf(y1) << 16) | f2bf(y0);
      *(unsigned int*)(lnm + n * 136 + c) = pk;
    }
  }
  __syncthreads();

  // ---- phase 1: wave w computes 64 rows x 64 cols of gelu(ln @ w1 + b1) ----
  f32x4 acc[4][4] = {};
#pragma unroll
  for (int ksi = 0; ksi < 4; ksi++) {
    int kof = ksi * 32 + g * 8;
    bf16x8 av[4], bv[4];
#pragma unroll
    for (int rt = 0; rt < 4; rt++)
      av[rt] = ld8(lnm + (rt * 16 + lr) * 136 + kof);
#pragma unroll
    for (int ct = 0; ct < 4; ct++) {
      int colc = w * 64 + ct * 16 + lr;
      bv[ct] = ld8(w1t + colc * 128 + kof);
    }
#pragma unroll
    for (int rt = 0; rt < 4; rt++)
#pragma unroll
      for (int ct = 0; ct < 4; ct++)
        acc[rt][ct] = __builtin_amdgcn_mfma_f32_16x16x32_bf16(av[rt], bv[ct], acc[rt][ct], 0, 0, 0);
  }
#pragma unroll
  for (int ct = 0; ct < 4; ct++) {
    int c = w * 64 + ct * 16 + lr;
    float bc = b1[c];
#pragma unroll
    for (int rt = 0; rt < 4; rt++)
#pragma unroll
      for (int rgi = 0; rgi < 4; rgi++) {
        int n = rt * 16 + g * 4 + rgi;
        float v = acc[rt][ct][rgi] + bc;
        float u = v * (1.0f + 0.044715f * v * v);
        float gv = v / (1.0f + __expf(-1.5957691216f * u));
        gel[n * 520 + c] = f2bf(gv);
      }
  }
  __syncthreads();

  // ---- phase 2: wave w computes 64 rows x 16 cols, K=512 -> dout + residual ----
  f32x4 a2[4] = {};
#pragma unroll 4
  for (int ksi = 0; ksi < 16; ksi++) {
    int kof = ksi * 32 + g * 8;
    bf16x8 aa[4];
#pragma unroll
    for (int rt = 0; rt < 4; rt++)
      aa[rt] = ld8(gel + (rt * 16 + lr) * 520 + kof);
    bf16x8 bb = ld8(w2t + (w * 16 + lr) * 512 + kof);
#pragma unroll
    for (int rt = 0; rt < 4; rt++)
      a2[rt] = __builtin_amdgcn_mfma_f32_16x16x32_bf16(aa[rt], bb, a2[rt], 0, 0, 0);
  }
  int col = w * 16 + lr;
  float bc2 = b2[col];
#pragma unroll
  for (int rt = 0; rt < 4; rt++)
#pragma unroll
    for (int rgi = 0; rgi < 4; rgi++) {
      long row = rowbase + rt * 16 + g * 4 + rgi;
      dout[row * 128 + col] = out1[row * 128 + col] + bc2 + a2[rt][rgi];
    }
}

// ---------- launch ----------
extern "C" void kernel_launch(void* const* d_in, const int* in_sizes, int n_in,
                              void* d_out, int out_size, void* d_ws, size_t ws_size,
                              hipStream_t stream) {
  (void)in_sizes; (void)n_in; (void)out_size; (void)ws_size;
  const float* x      = (const float*)d_in[0];
  const float* qkv_w  = (const float*)d_in[1];
  const float* qkv_b  = (const float*)d_in[2];
  const float* proj_w = (const float*)d_in[3];
  const float* proj_b = (const float*)d_in[4];
  const float* rpb    = (const float*)d_in[5];
  const float* ln1_w  = (const float*)d_in[6];
  const float* ln1_b  = (const float*)d_in[7];
  const float* ln2_w  = (const float*)d_in[8];
  const float* ln2_b  = (const float*)d_in[9];
  const float* w1     = (const float*)d_in[10];
  const float* b1     = (const float*)d_in[11];
  const float* w2     = (const float*)d_in[12];
  const float* b2     = (const float*)d_in[13];

  char* ws = (char*)d_ws;
  // layout (round-3 offsets):
  //   0        : weights bf16 (393216)
  //   393216   : hb [T][128] bf16  -- aliased by attno
  //   26083328 : qkv [T][384] bf16
  //   103153664: out1 [T][128] f32
  //   154533888: cls2 (256 KB)
  unsigned short* wts   = (unsigned short*)ws;
  unsigned short* hb    = (unsigned short*)(ws + 393216);
  unsigned short* qkv   = (unsigned short*)(ws + 26083328);
  unsigned short* attno = hb;                      // alias: hb dead after QKV gemm
  float*          out1  = (float*)(ws + 103153664);
  float*          cls2  = (float*)(ws + 154533888);

  const int MP = T_TOK / 128;   // 784 m-panels

  prep_weights<<<768, 256, 0, stream>>>(qkv_w, proj_w, w1, w2, wts);
  prep_cls<<<256, 256, 0, stream>>>(rpb, cls2);
  ln_kernel<true><<<T_TOK / 4, 256, 0, stream>>>(x, ln1_w, ln1_b, hb);
  gemm_k<0, 4, 6><<<MP * 6, 256, 0, stream>>>(hb, wts, qkv_b, qkv, nullptr);
  attn_mfma<<<NWIN, 256, 0, stream>>>(qkv, cls2, attno);
  gemm_k<1, 4, 2><<<MP * 2, 256, 0, stream>>>(attno, wts + 49152, proj_b, out1, x);
  mlp_fused<<<T_TOK / 64, 512, 0, stream>>>(out1, wts + 65536, b1, wts + 131072, b2,
                                            ln2_w, ln2_b, (float*)d_out);
}